// Round 1
// 135.906 us; speedup vs baseline: 1.0310x; 1.0310x over previous
//
#include <hip/hip_runtime.h>
#include <hip/hip_bf16.h>

#define B_SZ 128
#define IN_CAPS 1152
#define N_CAPS 16
#define DIM 16

#define IPB 8                         // i's per pass-block (1 i per chunk, dbuf)
#define ICN (IN_CAPS / IPB)           // 144 partial slices
#define OUT_ELEMS (B_SZ * N_CAPS * DIM)   // 32768
// LDS hat tile (bf16 pairs, uint units): [slot(2)][b(16)][n(16)][ep(8)]
#define NSTRU 12                      // n-stride: 8 uints + 4 pad (16B-aligned)
#define BSTRU 196                     // b-stride: 16*12 + 4  (16B-aligned, mod32=4)
#define SLOTU (16 * BSTRU)            // 3136 uints = 12.5 KB per slot

typedef __attribute__((ext_vector_type(8))) short bf16x8;   // MFMA A/B frag
typedef __attribute__((ext_vector_type(4))) float f32x4;    // MFMA C/D frag

__device__ __forceinline__ unsigned short f2bf(float f) {   // RNE
    unsigned u = __float_as_uint(f);
    u = u + 0x7fffu + ((u >> 16) & 1u);
    return (unsigned short)(u >> 16);
}
__device__ __forceinline__ unsigned pk2(float lo, float hi) {
    return ((unsigned)f2bf(hi) << 16) | f2bf(lo);
}
__device__ __forceinline__ unsigned cvtpk(float lo, float hi) {   // HW packed cvt (RNE)
    union { __hip_bfloat162 h; unsigned u; } c;
    c.h = __float22bfloat162_rn(make_float2(lo, hi));
    return c.u;
}

// DPP sums (VALU pipe — no DS traffic)
__device__ __forceinline__ float dpp_sum16(float v) {
    v += __int_as_float(__builtin_amdgcn_update_dpp(0, __float_as_int(v), 0xB1, 0xF, 0xF, true));
    v += __int_as_float(__builtin_amdgcn_update_dpp(0, __float_as_int(v), 0x4E, 0xF, 0xF, true));
    v += __int_as_float(__builtin_amdgcn_update_dpp(0, __float_as_int(v), 0x124, 0xF, 0xF, true));
    v += __int_as_float(__builtin_amdgcn_update_dpp(0, __float_as_int(v), 0x128, 0xF, 0xF, true));
    return v;
}
__device__ __forceinline__ float dpp_sum8(float v) {
    v += __int_as_float(__builtin_amdgcn_update_dpp(0, __float_as_int(v), 0xB1, 0xF, 0xF, true));
    v += __int_as_float(__builtin_amdgcn_update_dpp(0, __float_as_int(v), 0x4E, 0xF, 0xF, true));
    v += __int_as_float(__builtin_amdgcn_update_dpp(0, __float_as_int(v), 0x141, 0xF, 0xF, true));
    return v;
}

// ---- prep (fused): blocks [0,1152): W -> WB bf16; [1152,1728): x -> XT[i][b][d] bf16 ----
__global__ __launch_bounds__(256)
void conv_xw(const float* __restrict__ W, const float* __restrict__ x,
             unsigned short* __restrict__ WB, unsigned short* __restrict__ XT)
{
    const int tid = threadIdx.x;
    if (blockIdx.x < 1152) {
        size_t g = (size_t)blockIdx.x * 256 + tid;
        const float4* src = (const float4*)(W + g * 8);
        float4 a = src[0], b = src[1];
        uint4 o = {pk2(a.x, a.y), pk2(a.z, a.w), pk2(b.x, b.y), pk2(b.z, b.w)};
        *(uint4*)(WB + g * 8) = o;
    } else {
        const int bx = blockIdx.x - 1152;
        const int i = bx * 2 + (tid >> 7);
        const int b = tid & 127;
        const float4* src = (const float4*)(x + ((size_t)b * IN_CAPS + i) * 8);
        float4 a = src[0], c = src[1];
        uint4 o = {pk2(a.x, a.y), pk2(a.z, a.w), pk2(c.x, c.y), pk2(c.z, c.w)};
        *(uint4*)(XT + ((size_t)i * B_SZ + b) * 8) = o;
    }
}

// Produce one i of hat into a slot. Swapped MFMA roles: A = W (m = e), B = x
// (col = b, k>=8 rows zeroed). D: col(lane&15) = b, rows(reg) = e = 4q+r ->
// 4 consecutive e's IN REGISTER -> pack bf16 pairs -> one ds_write_b64.
__device__ __forceinline__ void produce_i(
    const unsigned short* __restrict__ XT, const unsigned short* __restrict__ WB,
    unsigned* __restrict__ slot, int i, int bt, int w, int q, int em)
{
    uint4 xu = {0u, 0u, 0u, 0u};
    if (q == 0)   // B[k>=8][*] = 0 kills A's k>=8 garbage
        xu = *(const uint4*)(XT + ((size_t)i * B_SZ + bt * 16 + em) * 8);
    union { uint4 u; bf16x8 v; } bx; bx.u = xu;
    #pragma unroll
    for (int np = 0; np < 4; ++np) {
        const int nn = 4 * w + np;
        bf16x8 av = *(const bf16x8*)(WB + (((size_t)nn * IN_CAPS + i) * DIM + em) * 8);
        f32x4 cz = {0.f, 0.f, 0.f, 0.f};
        f32x4 d = __builtin_amdgcn_mfma_f32_16x16x32_bf16(av, bx.v, cz, 0, 0, 0);
        // lane (q, em=b) holds hat[b=em][e=4q..4q+3] for capsule nn
        uint2 o = {cvtpk(d[0], d[1]), cvtpk(d[2], d[3])};
        *(uint2*)(slot + (size_t)em * BSTRU + nn * NSTRU + 2 * q) = o;
    }
}

// ---- pass 0, specialized: c = 1/16 is CONSTANT, so the pass is linear ->
// accumulate hat directly in the MFMA C operand across all 8 i's of the
// slice. No LDS, no barriers, no softmax, no bf16 round-trip. Writes the
// same partial[ic][b][n][e] bf16 layout (pre-scaled by 1/16) so
// caps_reduce<false> is unchanged. ----
__global__ __launch_bounds__(256)
void caps_pass0(const unsigned short* __restrict__ XT, const unsigned short* __restrict__ WB,
                unsigned short* __restrict__ partial)
{
    const int tid  = threadIdx.x;
    const int lane = tid & 63;
    const int w    = tid >> 6;
    const int em   = lane & 15;
    const int q    = lane >> 4;
    const int bt   = blockIdx.x;      // 0..7
    const int ic   = blockIdx.y;      // 0..143
    const int i0   = ic * IPB;

    f32x4 acc[4];
    #pragma unroll
    for (int np = 0; np < 4; ++np) acc[np] = (f32x4){0.f, 0.f, 0.f, 0.f};

    #pragma unroll
    for (int ch = 0; ch < IPB; ++ch) {
        const int i = i0 + ch;
        uint4 xu = {0u, 0u, 0u, 0u};
        if (q == 0)   // B[k>=8][*] = 0 kills A's k>=8 garbage
            xu = *(const uint4*)(XT + ((size_t)i * B_SZ + bt * 16 + em) * 8);
        union { uint4 u; bf16x8 v; } bx; bx.u = xu;
        #pragma unroll
        for (int np = 0; np < 4; ++np) {
            const int nn = 4 * w + np;
            bf16x8 av = *(const bf16x8*)(WB + (((size_t)nn * IN_CAPS + i) * DIM + em) * 8);
            acc[np] = __builtin_amdgcn_mfma_f32_16x16x32_bf16(av, bx.v, acc[np], 0, 0, 0);
        }
    }

    // lane (q,em) holds sum_i hat[b=em][e=4q+r][nn]; scale by c=1/16, pack bf16
    const int b_glb = bt * 16 + em;
    unsigned short* pp = partial + (((size_t)ic * B_SZ + b_glb) << 8);
    #pragma unroll
    for (int np = 0; np < 4; ++np) {
        const int nn = 4 * w + np;
        uint2 o = {cvtpk(acc[np][0] * 0.0625f, acc[np][1] * 0.0625f),
                   cvtpk(acc[np][2] * 0.0625f, acc[np][3] * 0.0625f)};
        *(uint2*)(pp + nn * 16 + 4 * q) = o;
    }
}

// ---- fused routing pass ----
// R9 lesson: 41.5KB LDS -> 2.25 blocks/CU + produce|barrier|consume|barrier
// exposed full WB-load latency every chunk (pass ~38us vs ~10us model). Now:
// hat bf16-packed (25KB, 2 slots) + true dbuf (produce ch+1 || consume ch,
// ONE barrier/chunk) so producer loads overlap consumer VALU.
// Consumer thread: n = lane&15, b_loc = 4*wave + (lane>>4); e fully in-thread.
// MODE 1: pr = squash(accA+B).  MODE 2: pr = sq(accA+B)+sq(accB+B).
template<int MODE>
__global__ __launch_bounds__(256)
void caps_pass(const unsigned short* __restrict__ XT, const unsigned short* __restrict__ WB,
               const float* __restrict__ Bb,
               const float* __restrict__ accA, const float* __restrict__ accB,
               unsigned short* __restrict__ partial)
{
    const int tid  = threadIdx.x;
    const int lane = tid & 63;
    const int w    = tid >> 6;
    const int em   = lane & 15;       // producer: m(A)=e; consumer: n
    const int q    = lane >> 4;
    const int bt   = blockIdx.x;      // 0..7
    const int ic   = blockIdx.y;      // 0..143
    const int i0   = ic * IPB;
    const int n    = em;
    const int b_loc = 4 * w + q;
    const int b_glb = bt * 16 + b_loc;

    __shared__ unsigned hatp[2 * SLOTU];   // 25.1 KB -> 6 blocks/CU (LDS)

    // ---- prologue: pr[e] for this thread's (b_glb, n) ----
    float pr[16];
    {
        const float4* bbp = (const float4*)(Bb + (n << 4));
        const float4* ap  = (const float4*)(accA + ((size_t)b_glb << 8) + (n << 4));
        float s[16], s2 = 0.f;
        #pragma unroll
        for (int k4 = 0; k4 < 4; ++k4) {
            float4 a = ap[k4], bb = bbp[k4];
            s[4*k4+0] = a.x + bb.x; s[4*k4+1] = a.y + bb.y;
            s[4*k4+2] = a.z + bb.z; s[4*k4+3] = a.w + bb.w;
        }
        #pragma unroll
        for (int e = 0; e < 16; ++e) s2 = fmaf(s[e], s[e], s2);
        float sc = sqrtf(s2) / (1.0f + s2);
        #pragma unroll
        for (int e = 0; e < 16; ++e) pr[e] = s[e] * sc;
        if (MODE == 2) {
            const float4* ap2 = (const float4*)(accB + ((size_t)b_glb << 8) + (n << 4));
            float t[16], t2 = 0.f;
            #pragma unroll
            for (int k4 = 0; k4 < 4; ++k4) {
                float4 a = ap2[k4], bb = bbp[k4];
                t[4*k4+0] = a.x + bb.x; t[4*k4+1] = a.y + bb.y;
                t[4*k4+2] = a.z + bb.z; t[4*k4+3] = a.w + bb.w;
            }
            #pragma unroll
            for (int e = 0; e < 16; ++e) t2 = fmaf(t[e], t[e], t2);
            float sc2 = sqrtf(t2) / (1.0f + t2);
            #pragma unroll
            for (int e = 0; e < 16; ++e) pr[e] = fmaf(t[e], sc2, pr[e]);
        }
        #pragma unroll
        for (int e = 0; e < 16; ++e)
            asm volatile("" : "+v"(pr[e]));   // pin: no remat across the chunk loop
    }

    float acc[16];
    #pragma unroll
    for (int e = 0; e < 16; ++e) acc[e] = 0.f;

    produce_i(XT, WB, hatp, i0, bt, w, q, em);   // chunk 0 -> slot 0

    #pragma unroll 1
    for (int ch = 0; ch < IPB; ++ch) {
        __syncthreads();
        if (ch + 1 < IPB)   // overlap: next chunk's loads+MFMA run against this consume
            produce_i(XT, WB, hatp + ((ch + 1) & 1) * SLOTU, i0 + ch + 1, bt, w, q, em);

        // ---- consume chunk ch (slot ch&1): e fully in-thread ----
        const unsigned* rowp = hatp + (ch & 1) * SLOTU + (size_t)b_loc * BSTRU + n * NSTRU;
        uint4 u0 = *(const uint4*)rowp;          // e 0..7 (bf16 pairs)
        uint4 u1 = *(const uint4*)(rowp + 4);    // e 8..15
        float h[16];
        {
            unsigned uu[8] = {u0.x, u0.y, u0.z, u0.w, u1.x, u1.y, u1.z, u1.w};
            #pragma unroll
            for (int j = 0; j < 8; ++j) {
                h[2*j]   = __uint_as_float(uu[j] << 16);
                h[2*j+1] = __uint_as_float(uu[j] & 0xFFFF0000u);
            }
        }
        float lg = 0.f;
        #pragma unroll
        for (int e = 0; e < 16; ++e) lg = fmaf(pr[e], h[e], lg);
        float p = __expf(lg);                 // |lg| small -> max-free (R7-R9 proven)
        float z = dpp_sum16(p);               // softmax over n = 16-lane DPP row
        float c = p * __builtin_amdgcn_rcpf(z);
        #pragma unroll
        for (int e = 0; e < 16; ++e) acc[e] = fmaf(c, h[e], acc[e]);
    }

    // ---- epilogue: bf16 partial[ic][b][n][e] (thread owns the row) ----
    unsigned short* pp = partial + (((size_t)ic * B_SZ + b_glb) << 8) + (n << 4);
    uint4 o0 = {pk2(acc[0], acc[1]),   pk2(acc[2], acc[3]),
                pk2(acc[4], acc[5]),   pk2(acc[6], acc[7])};
    uint4 o1 = {pk2(acc[8], acc[9]),   pk2(acc[10], acc[11]),
                pk2(acc[12], acc[13]), pk2(acc[14], acc[15])};
    *(uint4*)pp = o0;
    *(uint4*)(pp + 8) = o1;
}

// ---- reduce 144 bf16 slices. Grouped: 256 blocks x 256 thr; thread (grp=tid>>6)
// sums 36 slices at uint pos (2 els); LDS combine; FINAL adds B + squash (8-lane DPP). ----
template<bool FINAL>
__global__ __launch_bounds__(256)
void caps_reduce(const unsigned* __restrict__ partial, const float* __restrict__ Bb,
                 float2* __restrict__ acc, float2* __restrict__ out)
{
    const int tid = threadIdx.x;
    const int ps  = tid & 63;
    const int grp = tid >> 6;
    const int pos = blockIdx.x * 64 + ps;        // uint index in [0, 16384)

    float t0 = 0.f, t1 = 0.f;
    #pragma unroll 6
    for (int k = 0; k < ICN / 4; ++k) {
        unsigned u = partial[(size_t)(grp * (ICN / 4) + k) * (OUT_ELEMS / 2) + pos];
        t0 += __uint_as_float(u << 16);
        t1 += __uint_as_float(u & 0xFFFF0000u);
    }
    __shared__ float2 red[4][64];
    red[grp][ps] = make_float2(t0, t1);
    __syncthreads();

    if (tid < 64) {
        float2 a = red[0][ps], b = red[1][ps], c = red[2][ps], d = red[3][ps];
        float v0 = a.x + b.x + c.x + d.x;
        float v1 = a.y + b.y + c.y + d.y;
        if (!FINAL) {
            acc[pos] = make_float2(v0, v1);
        } else {
            const int n = (pos >> 3) & 15, ep = pos & 7;
            float2 bb = *(const float2*)(Bb + n * 16 + 2 * ep);
            v0 += bb.x; v1 += bb.y;
            float s2 = dpp_sum8(v0 * v0 + v1 * v1);   // e-row = 8 consecutive lanes
            float sc = sqrtf(s2) / (1.0f + s2);
            out[pos] = make_float2(v0 * sc, v1 * sc);
        }
    }
}

extern "C" void kernel_launch(void* const* d_in, const int* in_sizes, int n_in,
                              void* d_out, int out_size, void* d_ws, size_t ws_size,
                              hipStream_t stream)
{
    const float* x  = (const float*)d_in[0];   // [128,1152,8]
    const float* W  = (const float*)d_in[1];   // [16,1152,16,8]
    const float* Bb = (const float*)d_in[2];   // [16,16]
    float2* out = (float2*)d_out;              // [128,16,16] fp32

    float* accA = (float*)d_ws;                                   // 128 KB
    float* accB = accA + OUT_ELEMS;                               // 128 KB
    unsigned short* WB = (unsigned short*)(accB + OUT_ELEMS);     // 4.72 MB
    unsigned short* XT = WB + (size_t)N_CAPS * IN_CAPS * DIM * 8; // 2.36 MB
    unsigned short* partial = XT + (size_t)B_SZ * IN_CAPS * 8;    // 144 x 64 KB = 9.4 MB

    conv_xw<<<1728, 256, 0, stream>>>(W, x, WB, XT);

    dim3 pg(B_SZ / 16, ICN);   // 8 x 144 = 1152 blocks

    caps_pass0<<<pg, 256, 0, stream>>>(XT, WB, partial);
    caps_reduce<false><<<256, 256, 0, stream>>>((const unsigned*)partial, Bb, (float2*)accA, nullptr);
    caps_pass<1><<<pg, 256, 0, stream>>>(XT, WB, Bb, accA, nullptr, partial);
    caps_reduce<false><<<256, 256, 0, stream>>>((const unsigned*)partial, Bb, (float2*)accB, nullptr);
    caps_pass<2><<<pg, 256, 0, stream>>>(XT, WB, Bb, accA, accB, partial);
    caps_reduce<true><<<256, 256, 0, stream>>>((const unsigned*)partial, Bb, nullptr, out);
}